// Round 4
// baseline (254.194 us; speedup 1.0000x reference)
//
#include <hip/hip_runtime.h>

// LTC cell: B=1024, I=128, N=256, 6 unfolds.
// Round 8: TWO INDEPENDENT BLOCKS PER CU. Invariant found in R0/R6/R7:
// VALUBusy*dur == ~88-90us of issue in every variant -> kernel is pure
// issue-bound; duration == issue/busy%. The 23% idle is block-wide barrier
// drains (all 4 waves/SIMD stall together, 13 barriers). Fix: grid 512 of
// 512-thread blocks, 2 batches each (NO cross-block deps, unlike R6's
// n-split) -> when block A barriers, block B's waves keep issuing.
// Weight stream doubles per CU; compensated by packing {W, W*erev} as a
// bf16 pair (12B/elem) -> per-XCD L2 ~3.0 TB/s (~70% of ceiling).
// A = sigma*log2e and B = sigma*mu*log2e stay f32 (exp2-arg precision).

#define LOG2E 1.44269504088896340f

constexpr int Bn = 1024;
constexpr int In = 128;
constexpr int Nn = 256;
constexpr int UNFOLDS = 6;

#if __has_builtin(__builtin_amdgcn_exp2f)
#define EXP2F(x) __builtin_amdgcn_exp2f(x)
#else
#define EXP2F(x) __exp2f(x)
#endif
#if __has_builtin(__builtin_amdgcn_rcpf)
#define RCPF(x) __builtin_amdgcn_rcpf(x)
#else
#define RCPF(x) (1.0f / (x))
#endif

// Round-to-nearest-even bf16 pair pack: hi16 = W, lo16 = W*erev.
__device__ __forceinline__ unsigned int pack_bf16_pair(float w, float we) {
    unsigned int uw = __float_as_uint(w);
    unsigned int ue = __float_as_uint(we);
    uw = (uw + 0x7fffu + ((uw >> 16) & 1u)) & 0xffff0000u;
    ue = (ue + 0x7fffu + ((ue >> 16) & 1u)) >> 16;
    return uw | ue;
}

// ---------------------------------------------------------------------------
// Pack. Recurrent: PAB[i*N+n] = {sigma*log2e, sigma*mu*log2e} (f32),
//                  PWE[i*N+n] = bf16(W)<<16 | bf16(W*erev).
// Sensory: SAB / SWE same layout over [I][N].
// sigmoid(sigma*(v-mu)) = 1/(1 + exp2(B - A*v)).
// ---------------------------------------------------------------------------
__global__ __launch_bounds__(256) void pack_kernel(
    const float* __restrict__ mu, const float* __restrict__ sigma,
    const float* __restrict__ W, const float* __restrict__ erev,
    const float* __restrict__ smu, const float* __restrict__ ssigma,
    const float* __restrict__ sW, const float* __restrict__ serev,
    float2* __restrict__ PAB, unsigned int* __restrict__ PWE,
    float2* __restrict__ SAB, unsigned int* __restrict__ SWE) {
    int idx = blockIdx.x * 256 + threadIdx.x;
    if (idx < Nn * Nn) {
        float s = sigma[idx], m = mu[idx], w = W[idx], e = erev[idx];
        PAB[idx] = make_float2(s * LOG2E, s * m * LOG2E);
        PWE[idx] = pack_bf16_pair(w, w * e);
        return;
    }
    int j = idx - Nn * Nn;
    if (j < In * Nn) {
        float s = ssigma[j], m = smu[j], w = sW[j], e = serev[j];
        SAB[j] = make_float2(s * LOG2E, s * m * LOG2E);
        SWE[j] = pack_bf16_pair(w, w * e);
    }
}

// ---------------------------------------------------------------------------
// Fused LTC kernel: 512 blocks x 512 threads. Block = 2 batches x 256 n.
// Thread layout: n = tid&255, ih = tid>>8 (0..1, i-slice; also bb for reduce).
// Per thread per unfold: 128 i-iters x 2 batches = 256 sigmoid evals.
// LDS ~11 KB/block: vt[256] float2 (v for 2 batches), xs[128] float2,
// part[2][2][256] float2. Two blocks/CU interleave across barriers.
// ---------------------------------------------------------------------------
__global__ __launch_bounds__(512, 4) void ltc_fused_kernel(
    const float* __restrict__ inputs, const float* __restrict__ state,
    const float* __restrict__ input_w, const float* __restrict__ input_b,
    const float2* __restrict__ SAB, const unsigned int* __restrict__ SWE,
    const float2* __restrict__ PAB, const unsigned int* __restrict__ PWE,
    const float* __restrict__ vleak, const float* __restrict__ gleak,
    const float* __restrict__ cmt, float* __restrict__ out) {
    __shared__ float2 vt[Nn];            // [i] -> 2 batches, 2 KB
    __shared__ float2 xs[In];            // sensory x, [i] -> 2 batches, 1 KB
    __shared__ float2 part[2][2][Nn];    // [ih][bb][n] = {num,den}, 8 KB

    const int tid = threadIdx.x;
    const int b0 = blockIdx.x * 2;
    const int n = tid & 255;
    const int ih = tid >> 8;             // 0..1 : i-slice; bb for reduce

    // ---- fill: v state (this thread's (bb=ih, n) value) + sensory x ----
    float vp = state[(b0 + ih) * Nn + n];            // coalesced
    ((float*)vt)[n * 2 + ih] = vp;
    if (tid < 2 * In) {
        int i = tid & 127, bb = tid >> 7;            // bb in 0..1
        ((float*)xs)[i * 2 + bb] =
            inputs[(b0 + bb) * In + i] * input_w[i] + input_b[i];
    }
    const float g = gleak[n], c = cmt[n];
    const float gvl = g * vleak[n];
    __syncthreads();

    // ---- sensory sums (i = 0..127, slice 64 per ih) ----
    float sens_n, sens_d;
    {
        float num0 = 0.f, num1 = 0.f, den0 = 0.f, den1 = 0.f;
        const float2* __restrict__ ab = SAB + n;
        const unsigned int* __restrict__ we = SWE + n;
#pragma unroll 8
        for (int i = ih * 64; i < ih * 64 + 64; ++i) {
            float2 p = ab[i * Nn];                   // coalesced dwordx2
            unsigned int wp = we[i * Nn];            // coalesced dword
            float2 v = xs[i];                        // ds b64 broadcast
            float Wv  = __uint_as_float(wp & 0xffff0000u);
            float Wev = __uint_as_float(wp << 16);
            float r0 = RCPF(1.0f + EXP2F(fmaf(-p.x, v.x, p.y)));
            float r1 = RCPF(1.0f + EXP2F(fmaf(-p.x, v.y, p.y)));
            den0 += Wv * r0;  num0 += Wev * r0;
            den1 += Wv * r1;  num1 += Wev * r1;
        }
        part[ih][0][n] = make_float2(num0, den0);
        part[ih][1][n] = make_float2(num1, den1);
        __syncthreads();
        float2 p0 = part[0][ih][n], p1 = part[1][ih][n];  // this bb == ih
        sens_n = p0.x + p1.x;
        sens_d = p0.y + p1.y;
    }

    // ---- 6 unfolds ----
    const float2* __restrict__ ab = PAB + n;
    const unsigned int* __restrict__ wep = PWE + n;
    for (int s = 0; s < UNFOLDS; ++s) {
        __syncthreads();  // vt writes from prev step visible; part reusable
        float num0 = 0.f, num1 = 0.f, den0 = 0.f, den1 = 0.f;
#pragma unroll 8
        for (int i = ih * 128; i < ih * 128 + 128; ++i) {
            float2 p = ab[i * Nn];                   // coalesced dwordx2 (L2)
            unsigned int wp = wep[i * Nn];           // coalesced dword (L2)
            float2 v = vt[i];                        // ds b64 broadcast
            float Wv  = __uint_as_float(wp & 0xffff0000u);
            float Wev = __uint_as_float(wp << 16);
            float r0 = RCPF(1.0f + EXP2F(fmaf(-p.x, v.x, p.y)));
            float r1 = RCPF(1.0f + EXP2F(fmaf(-p.x, v.y, p.y)));
            den0 += Wv * r0;  num0 += Wev * r0;
            den1 += Wv * r1;  num1 += Wev * r1;
        }
        part[ih][0][n] = make_float2(num0, den0);
        part[ih][1][n] = make_float2(num1, den1);
        __syncthreads();
        // reduce for this thread's (bb=ih, n)
        float2 p0 = part[0][ih][n], p1 = part[1][ih][n];
        float wn = sens_n + p0.x + p1.x;
        float wd = sens_d + p0.y + p1.y;
        float res = (c * vp + gvl + wn) * RCPF(c + g + wd);
        vp = res;
        if (s == UNFOLDS - 1)
            out[(b0 + ih) * Nn + n] = res;           // coalesced final store
        else
            ((float*)vt)[n * 2 + ih] = res;
    }
}

// ---------------------------------------------------------------------------
extern "C" void kernel_launch(void* const* d_in, const int* in_sizes, int n_in,
                              void* d_out, int out_size, void* d_ws, size_t ws_size,
                              hipStream_t stream) {
    const float* inputs   = (const float*)d_in[0];
    const float* state    = (const float*)d_in[1];
    const float* input_w  = (const float*)d_in[2];
    const float* input_b  = (const float*)d_in[3];
    const float* smu      = (const float*)d_in[4];
    const float* ssigma   = (const float*)d_in[5];
    const float* sW       = (const float*)d_in[6];
    const float* serev    = (const float*)d_in[7];
    const float* mu       = (const float*)d_in[8];
    const float* sigma    = (const float*)d_in[9];
    const float* W        = (const float*)d_in[10];
    const float* erev     = (const float*)d_in[11];
    const float* vleak    = (const float*)d_in[12];
    const float* gleak    = (const float*)d_in[13];
    const float* cmt      = (const float*)d_in[14];
    float* out = (float*)d_out;

    // Workspace: PAB 512K | PWE 256K | SAB 256K | SWE 128K  (total 1.125 MiB)
    char* ws = (char*)d_ws;
    float2*       PAB = (float2*)(ws);
    unsigned int* PWE = (unsigned int*)(ws + (512u << 10));
    float2*       SAB = (float2*)(ws + (768u << 10));
    unsigned int* SWE = (unsigned int*)(ws + (1024u << 10));

    pack_kernel<<<(Nn * Nn + In * Nn + 255) / 256, 256, 0, stream>>>(
        mu, sigma, W, erev, smu, ssigma, sW, serev, PAB, PWE, SAB, SWE);

    // 512 blocks of 512 threads -> 2 independent blocks per CU.
    ltc_fused_kernel<<<Bn / 2, 512, 0, stream>>>(
        inputs, state, input_w, input_b, SAB, SWE, PAB, PWE,
        vleak, gleak, cmt, out);
}